// Round 1
// baseline (1489.828 us; speedup 1.0000x reference)
//
#include <hip/hip_runtime.h>
#include <hip/hip_bf16.h>
#include <stdint.h>

// SageConv: out = [features | (adj@features)/(rowsum(adj)+1)] @ W^T
// N=16384, F_IN=64, F_OUT=64. adj is 1.07 GB fp32 read once -> HBM-bound.
// Strategy: bf16 MFMA for adj@features (threshold 0.87 allows it), deg from
// the same registers, fused epilogue. Floor ~= 1.07GB / 6.3 TB/s ~= 170 us.

#define NN 16384
#define FIN 64
#define WAVES_PB 4
#define ROWS_PB 16
#define K_PER_WAVE (NN / WAVES_PB)        // 4096
#define STEPS_PER_WAVE (K_PER_WAVE / 32)  // 128

typedef short short8 __attribute__((ext_vector_type(8)));
typedef float f32x4 __attribute__((ext_vector_type(4)));

__device__ __forceinline__ uint32_t pack2bf(float lo, float hi) {
    __hip_bfloat162 h = __float22bfloat162_rn(make_float2(lo, hi));
    union { __hip_bfloat162 h2; uint32_t u; } c;
    c.h2 = h;
    return c.u;
}

// Pack features [K=16384][64] fp32 into MFMA B-fragment order (bf16):
// entry ((kstep*4 + ntile)*64 + lane) holds 8 bf16 =
//   features[kstep*32 + (lane>>4)*8 + j][ntile*16 + (lane&15)], j=0..7
__global__ void prepack_b(const float* __restrict__ feat, uint4* __restrict__ packB) {
    int t = blockIdx.x * blockDim.x + threadIdx.x;  // 0..131071
    int lane  = t & 63;
    int ntile = (t >> 6) & 3;
    int kstep = t >> 8;
    int k0  = kstep * 32 + (lane >> 4) * 8;
    int col = ntile * 16 + (lane & 15);
    const float* p = feat + (size_t)k0 * FIN + col;
    uint32_t w0 = pack2bf(p[0 * FIN], p[1 * FIN]);
    uint32_t w1 = pack2bf(p[2 * FIN], p[3 * FIN]);
    uint32_t w2 = pack2bf(p[4 * FIN], p[5 * FIN]);
    uint32_t w3 = pack2bf(p[6 * FIN], p[7 * FIN]);
    packB[t] = make_uint4(w0, w1, w2, w3);
}

__global__ __launch_bounds__(256, 4)
void sage_main(const float* __restrict__ feat, const float* __restrict__ adj,
               const float* __restrict__ W, const uint4* __restrict__ packB,
               float* __restrict__ out) {
    __shared__ float red[WAVES_PB][ROWS_PB][64];   // 16 KB
    __shared__ float degred[WAVES_PB][ROWS_PB];
    __shared__ float degf[ROWS_PB];

    const int tid  = threadIdx.x;
    const int wave = tid >> 6;
    const int lane = tid & 63;
    const int quad = lane >> 4;
    const int l15  = lane & 15;
    const int rowbase = blockIdx.x * ROWS_PB;

    f32x4 acc0 = {0.f, 0.f, 0.f, 0.f};
    f32x4 acc1 = {0.f, 0.f, 0.f, 0.f};
    f32x4 acc2 = {0.f, 0.f, 0.f, 0.f};
    f32x4 acc3 = {0.f, 0.f, 0.f, 0.f};
    float dg0 = 0.f, dg1 = 0.f;

    // A: lane holds adj[rowbase + (lane&15)][k0 + quad*8 .. +7]  (8 consecutive fp32)
    const float* aptr = adj + (size_t)(rowbase + l15) * NN + wave * K_PER_WAVE + quad * 8;
    const uint4* bptr = packB + ((size_t)(wave * STEPS_PER_WAVE) * 4) * 64 + lane;

#pragma unroll 2
    for (int s = 0; s < STEPS_PER_WAVE; ++s) {
        float4 a0 = *(const float4*)(aptr);
        float4 a1 = *(const float4*)(aptr + 4);
        union { uint4 u4; short8 s8; } b0, b1, b2, b3;
        b0.u4 = bptr[0];
        b1.u4 = bptr[64];
        b2.u4 = bptr[128];
        b3.u4 = bptr[192];

        dg0 += (a0.x + a0.y) + (a0.z + a0.w);
        dg1 += (a1.x + a1.y) + (a1.z + a1.w);

        union { uint32_t u[4]; short8 s8; } af;
        af.u[0] = pack2bf(a0.x, a0.y);
        af.u[1] = pack2bf(a0.z, a0.w);
        af.u[2] = pack2bf(a1.x, a1.y);
        af.u[3] = pack2bf(a1.z, a1.w);

        acc0 = __builtin_amdgcn_mfma_f32_16x16x32_bf16(af.s8, b0.s8, acc0, 0, 0, 0);
        acc1 = __builtin_amdgcn_mfma_f32_16x16x32_bf16(af.s8, b1.s8, acc1, 0, 0, 0);
        acc2 = __builtin_amdgcn_mfma_f32_16x16x32_bf16(af.s8, b2.s8, acc2, 0, 0, 0);
        acc3 = __builtin_amdgcn_mfma_f32_16x16x32_bf16(af.s8, b3.s8, acc3, 0, 0, 0);

        aptr += 32;
        bptr += 256;
    }

    // deg: lanes {l, l^16, l^32, l^48} cover the same adj row
    float dg = dg0 + dg1;
    dg += __shfl_xor(dg, 16, 64);
    dg += __shfl_xor(dg, 32, 64);
    if (lane < 16) degred[wave][lane] = dg;

    // C/D layout: row = quad*4 + reg, col = lane&15 (+16*ntile)
#pragma unroll
    for (int r = 0; r < 4; ++r) {
        red[wave][quad * 4 + r][l15]      = acc0[r];
        red[wave][quad * 4 + r][16 + l15] = acc1[r];
        red[wave][quad * 4 + r][32 + l15] = acc2[r];
        red[wave][quad * 4 + r][48 + l15] = acc3[r];
    }
    __syncthreads();

    // cross-wave reduce: each thread owns 4 flat positions (same across waves)
#pragma unroll
    for (int i = 0; i < 4; ++i) {
        int pos = tid + i * 256;
        int r = pos >> 6, c = pos & 63;
        float v = red[0][r][c] + red[1][r][c] + red[2][r][c] + red[3][r][c];
        red[0][r][c] = v;
    }
    if (tid < 16) {
        degf[tid] = degred[0][tid] + degred[1][tid] + degred[2][tid] + degred[3][tid] + 1.0f;
    }
    __syncthreads();

    // Epilogue: out[grow][n] = feat_row . W[n][0:64] + (neigh_row . W[n][64:128]) / deg
    const int row  = tid >> 4;   // 0..15
    const int n0   = tid & 15;
    const int grow = rowbase + row;
    const float* frow = feat + (size_t)grow * FIN;
    const float4* nrow4 = (const float4*)red[0][row];
    const float inv = 1.0f / degf[row];

#pragma unroll
    for (int q = 0; q < 4; ++q) {
        int n = n0 + q * 16;
        const float* wr = W + n * 128;
        float s = 0.f, sn = 0.f;
#pragma unroll
        for (int j = 0; j < 64; j += 4) {
            float4 f4  = *(const float4*)(frow + j);
            float4 w4  = *(const float4*)(wr + j);
            float4 wn4 = *(const float4*)(wr + 64 + j);
            float4 nb  = nrow4[j >> 2];
            s  += f4.x * w4.x + f4.y * w4.y + f4.z * w4.z + f4.w * w4.w;
            sn += nb.x * wn4.x + nb.y * wn4.y + nb.z * wn4.z + nb.w * wn4.w;
        }
        out[(size_t)grow * FIN + n] = s + sn * inv;
    }
}

extern "C" void kernel_launch(void* const* d_in, const int* in_sizes, int n_in,
                              void* d_out, int out_size, void* d_ws, size_t ws_size,
                              hipStream_t stream) {
    const float* feat = (const float*)d_in[0];
    const float* adj  = (const float*)d_in[1];
    const float* W    = (const float*)d_in[2];
    float* outp = (float*)d_out;
    uint4* packB = (uint4*)d_ws;  // 2 MB

    prepack_b<<<512, 256, 0, stream>>>(feat, packB);
    sage_main<<<1024, 256, 0, stream>>>(feat, adj, W, packB, outp);
}